// Round 5
// baseline (178.308 us; speedup 1.0000x reference)
//
#include <hip/hip_runtime.h>

#define NN   100000
#define KK   32
#define DIN  128
#define DOUT 64
#define NEGV (-9e15f)

typedef __attribute__((ext_vector_type(8))) short bf16x8;   // 4 VGPRs
typedef __attribute__((ext_vector_type(4))) float f32x4;

__device__ __forceinline__ float bflo(unsigned u) { return __uint_as_float(u << 16); }
__device__ __forceinline__ float bfhi(unsigned u) { return __uint_as_float(u & 0xffff0000u); }
__device__ __forceinline__ ushort f2bf(float f) {            // round-to-nearest-even
    unsigned u = __float_as_uint(f);
    return (ushort)((u + 0x7fffu + ((u >> 16) & 1u)) >> 16);
}
__device__ __forceinline__ unsigned pk2(float a, float b) {  // [bf16(a) | bf16(b)<<16]
    unsigned r;
    asm("v_cvt_pk_bf16_f32 %0, %1, %2" : "=v"(r) : "v"(a), "v"(b));
    return r;
}
__device__ __forceinline__ bf16x8 cvt8(float4 a, float4 b) {
    union { unsigned u[4]; bf16x8 v; } r;
    r.u[0] = pk2(a.x, a.y); r.u[1] = pk2(a.z, a.w);
    r.u[2] = pk2(b.x, b.y); r.u[3] = pk2(b.z, b.w);
    return r.v;
}

// ---------------------------------------------------------------------------
// Kernel 0: xb = bf16(x). Pure streaming (51.2 MB read, 25.6 MB write).
// Exists so h_kernel's A-fragment loads become contiguous 16B/lane b128
// (f32 k-slices are 32B/lane -> 2 strided 16B loads -> 64 scattered
// transactions per instruction; bf16 k-slices give 16 rows x 64B contig).
// ---------------------------------------------------------------------------
__global__ __launch_bounds__(256) void x2b_kernel(const float* __restrict__ x,
                                                  ushort* __restrict__ xb) {
    const int total = NN * DIN / 4;                 // 3.2M float4
    const float4* xp = reinterpret_cast<const float4*>(x);
    uint2* op = reinterpret_cast<uint2*>(xb);
    for (int i = blockIdx.x * blockDim.x + threadIdx.x; i < total;
         i += gridDim.x * blockDim.x) {
        const float4 v = xp[i];
        uint2 o;
        o.x = pk2(v.x, v.y);
        o.y = pk2(v.z, v.w);
        op[i] = o;
    }
}

// ---------------------------------------------------------------------------
// Kernel A (MFMA): hb = bf16(xb @ W^T + b), hb[0][:] = bf16(NEGV)
// A-frags: one b128 per kstep straight from bf16 x (16 rows x 64B contiguous
// per instruction). B (W) cvt'd once into 64 VGPRs. Bias folded at store.
// C/D mapping col=lane&15, row=(lane>>4)*4+reg (m89/m91-verified).
// ---------------------------------------------------------------------------
__global__ __launch_bounds__(256) void h_kernel_bf16(const ushort* __restrict__ xb,
                                                     const float* __restrict__ W,
                                                     const float* __restrict__ b,
                                                     ushort* __restrict__ hb) {
    const int t    = threadIdx.x;
    const int w    = t >> 6;
    const int lane = t & 63;
    const int lr   = lane & 15;
    const int lg   = lane >> 4;

    bf16x8 Bf[4][4];
    const float* wp = W + (size_t)lr * DIN + lg * 8;
#pragma unroll
    for (int ct = 0; ct < 4; ++ct)
#pragma unroll
        for (int ks = 0; ks < 4; ++ks) {
            const float* p = wp + ct * 16 * DIN + ks * 32;
            Bf[ct][ks] = cvt8(*(const float4*)p, *(const float4*)(p + 4));
        }

    float bias[4];
#pragma unroll
    for (int ct = 0; ct < 4; ++ct) bias[ct] = b[ct * 16 + lr];

    const int base = blockIdx.x * 128 + w * 16;
#pragma unroll
    for (int tile = 0; tile < 2; ++tile) {
        const int row0 = base + tile * 64;

        int ar = row0 + lr;
        if (ar > NN - 1) ar = NN - 1;
        const ushort* xp = xb + (size_t)ar * DIN + lg * 8;

        bf16x8 Af[4];
#pragma unroll
        for (int ks = 0; ks < 4; ++ks)
            Af[ks] = *(const bf16x8*)(xp + ks * 32);

        f32x4 acc[4] = {{0.f,0.f,0.f,0.f},{0.f,0.f,0.f,0.f},
                        {0.f,0.f,0.f,0.f},{0.f,0.f,0.f,0.f}};
#pragma unroll
        for (int ct = 0; ct < 4; ++ct)
#pragma unroll
            for (int ks = 0; ks < 4; ++ks)
                acc[ct] = __builtin_amdgcn_mfma_f32_16x16x32_bf16(
                    Af[ks], Bf[ct][ks], acc[ct], 0, 0, 0);

#pragma unroll
        for (int ct = 0; ct < 4; ++ct)
#pragma unroll
            for (int j = 0; j < 4; ++j) {
                const int m = row0 + lg * 4 + j;
                if (m < NN) {
                    const float v = (m == 0) ? NEGV : (acc[ct][j] + bias[ct]);
                    hb[(size_t)m * DOUT + ct * 16 + lr] = f2bf(v);
                }
            }
    }
}

// Fallback (reads f32 x directly) if ws can't hold the bf16 x copy.
__global__ __launch_bounds__(256) void h_kernel_f32(const float* __restrict__ x,
                                                    const float* __restrict__ W,
                                                    const float* __restrict__ b,
                                                    ushort* __restrict__ hb) {
    const int t    = threadIdx.x;
    const int w    = t >> 6;
    const int lane = t & 63;
    const int lr   = lane & 15;
    const int lg   = lane >> 4;

    bf16x8 Bf[4][4];
    const float* wp = W + (size_t)lr * DIN + lg * 8;
#pragma unroll
    for (int ct = 0; ct < 4; ++ct)
#pragma unroll
        for (int ks = 0; ks < 4; ++ks) {
            const float* p = wp + ct * 16 * DIN + ks * 32;
            Bf[ct][ks] = cvt8(*(const float4*)p, *(const float4*)(p + 4));
        }

    float bias[4];
#pragma unroll
    for (int ct = 0; ct < 4; ++ct) bias[ct] = b[ct * 16 + lr];

    const int base = blockIdx.x * 128 + w * 16;
#pragma unroll
    for (int tile = 0; tile < 2; ++tile) {
        const int row0 = base + tile * 64;
        int ar = row0 + lr;
        if (ar > NN - 1) ar = NN - 1;
        const float* xp = x + (size_t)ar * DIN + lg * 8;

        bf16x8 Af[4];
#pragma unroll
        for (int ks = 0; ks < 4; ++ks)
            Af[ks] = cvt8(*(const float4*)(xp + ks * 32),
                          *(const float4*)(xp + ks * 32 + 4));

        f32x4 acc[4] = {{0.f,0.f,0.f,0.f},{0.f,0.f,0.f,0.f},
                        {0.f,0.f,0.f,0.f},{0.f,0.f,0.f,0.f}};
#pragma unroll
        for (int ct = 0; ct < 4; ++ct)
#pragma unroll
            for (int ks = 0; ks < 4; ++ks)
                acc[ct] = __builtin_amdgcn_mfma_f32_16x16x32_bf16(
                    Af[ks], Bf[ct][ks], acc[ct], 0, 0, 0);

#pragma unroll
        for (int ct = 0; ct < 4; ++ct)
#pragma unroll
            for (int j = 0; j < 4; ++j) {
                const int m = row0 + lg * 4 + j;
                if (m < NN) {
                    const float v = (m == 0) ? NEGV : (acc[ct][j] + bias[ct]);
                    hb[(size_t)m * DOUT + ct * 16 + lr] = f2bf(v);
                }
            }
    }
}

// ---------------------------------------------------------------------------
// Kernel B (MFMA gather-attention, 1 row/wave for max TLP):
// 32 neighbor dots = 4 x mfma_f32_16x16x32_bf16 with h[n] broadcast into all
// 16 B-columns; D holds each dot duplicated across columns -> reductions are
// 2 shuffles (xor16, xor32) over the 4 k-groups. Round-4 math, round-3 grid.
// ---------------------------------------------------------------------------
__global__ __launch_bounds__(256) void att_kernel(const ushort* __restrict__ hb,
                                                  const int* __restrict__ a2a,
                                                  float* __restrict__ out) {
    const int t    = threadIdx.x;
    const int wid  = t >> 6;
    const int lane = t & 63;
    const int lr   = lane & 15;
    const int lg   = lane >> 4;
    const int n    = blockIdx.x * 4 + wid;          // 25000 blocks * 4 rows

    const ushort* hbn = hb + (size_t)n * DOUT;

    // neighbor indices for the two 16-row tiles (issue gathers ASAP)
    const int i0 = a2a[n * KK + lr];
    const int i1 = a2a[n * KK + 16 + lr];
    const ushort* p0 = hb + (size_t)i0 * DOUT + lg * 8;
    const ushort* p1 = hb + (size_t)i1 * DOUT + lg * 8;

    const bf16x8 A00 = *(const bf16x8*)p0;          // tile0, k 0..31
    const bf16x8 A01 = *(const bf16x8*)(p0 + 32);   // tile0, k 32..63
    const bf16x8 A10 = *(const bf16x8*)p1;          // tile1, k 0..31
    const bf16x8 A11 = *(const bf16x8*)(p1 + 32);   // tile1, k 32..63

    // B fragments: h[n][lg*8..+8] and h[n][32+lg*8..+8], col-duplicated
    const bf16x8 B0 = *(const bf16x8*)(hbn + lg * 8);
    const bf16x8 B1 = *(const bf16x8*)(hbn + 32 + lg * 8);
    const float hv = bflo((unsigned)hbn[lane]);     // own value for output

    f32x4 d0 = {0.f, 0.f, 0.f, 0.f};
    f32x4 d1 = {0.f, 0.f, 0.f, 0.f};
    d0 = __builtin_amdgcn_mfma_f32_16x16x32_bf16(A00, B0, d0, 0, 0, 0);
    d0 = __builtin_amdgcn_mfma_f32_16x16x32_bf16(A01, B1, d0, 0, 0, 0);
    d1 = __builtin_amdgcn_mfma_f32_16x16x32_bf16(A10, B0, d1, 0, 0, 0);
    d1 = __builtin_amdgcn_mfma_f32_16x16x32_bf16(A11, B1, d1, 0, 0, 0);

    // self-dot from the B fragments (16 elems/lane; reduce across k-groups)
    union { bf16x8 v; unsigned u[4]; } ub0, ub1;
    ub0.v = B0; ub1.v = B1;
    float sp = 0.f;
#pragma unroll
    for (int i = 0; i < 4; ++i) {
        float a = bflo(ub0.u[i]), c = bfhi(ub0.u[i]);
        float e = bflo(ub1.u[i]), g = bfhi(ub1.u[i]);
        sp = fmaf(a, a, sp); sp = fmaf(c, c, sp);
        sp = fmaf(e, e, sp); sp = fmaf(g, g, sp);
    }
    sp += __shfl_xor(sp, 16);
    sp += __shfl_xor(sp, 32);

    float m = fmaxf(fmaxf(fmaxf(d0[0], d0[1]), fmaxf(d0[2], d0[3])),
                    fmaxf(fmaxf(d1[0], d1[1]), fmaxf(d1[2], d1[3])));
    m = fmaxf(m, __shfl_xor(m, 16));
    m = fmaxf(m, __shfl_xor(m, 32));
    m = fmaxf(m, sp);

    // per lr-column slice, lg*4+j covers each tile's 16 neighbors exactly once
    float s = __expf(d0[0] - m) + __expf(d0[1] - m) +
              __expf(d0[2] - m) + __expf(d0[3] - m) +
              __expf(d1[0] - m) + __expf(d1[1] - m) +
              __expf(d1[2] - m) + __expf(d1[3] - m);
    s += __shfl_xor(s, 16);
    s += __shfl_xor(s, 32);

    const float es = __expf(sp - m);
    const float w0 = es / (es + s);

    float o = hv * w0;
    if (n == 0) o = 0.f;
    out[(size_t)n * DOUT + lane] = o;
}

extern "C" void kernel_launch(void* const* d_in, const int* in_sizes, int n_in,
                              void* d_out, int out_size, void* d_ws, size_t ws_size,
                              hipStream_t stream) {
    const float* x   = (const float*)d_in[0];
    const int*   a2a = (const int*)d_in[1];
    const float* W   = (const float*)d_in[2];
    const float* b   = (const float*)d_in[3];
    float*       out = (float*)d_out;

    const size_t hb_bytes = (size_t)NN * DOUT * 2;        // 12.8 MB
    const size_t need     = hb_bytes + (size_t)NN * DIN * 2;  // + 25.6 MB
    ushort* hb = (ushort*)d_ws;

    if (ws_size >= need) {
        ushort* xb = (ushort*)((char*)d_ws + hb_bytes);
        x2b_kernel<<<2048, 256, 0, stream>>>(x, xb);
        h_kernel_bf16<<<(NN + 127) / 128, 256, 0, stream>>>(xb, W, b, hb);
    } else {
        h_kernel_f32<<<(NN + 127) / 128, 256, 0, stream>>>(x, W, b, hb);
    }
    att_kernel<<<NN / 4, 256, 0, stream>>>(hb, a2a, out);
}

// Round 10
// 169.538 us; speedup vs baseline: 1.0517x; 1.0517x over previous
//
#include <hip/hip_runtime.h>

#define NN   100000
#define KK   32
#define DIN  128
#define DOUT 64
#define NEGV (-9e15f)

typedef __attribute__((ext_vector_type(8))) short bf16x8;   // 4 VGPRs
typedef __attribute__((ext_vector_type(4))) float f32x4;

__device__ __forceinline__ float bflo(unsigned u) { return __uint_as_float(u << 16); }
__device__ __forceinline__ float bfhi(unsigned u) { return __uint_as_float(u & 0xffff0000u); }
__device__ __forceinline__ ushort f2bf(float f) {            // round-to-nearest-even
    unsigned u = __float_as_uint(f);
    return (ushort)((u + 0x7fffu + ((u >> 16) & 1u)) >> 16);
}
__device__ __forceinline__ unsigned pk2(float a, float b) {  // [bf16(a) | bf16(b)<<16]
    unsigned r;
    asm("v_cvt_pk_bf16_f32 %0, %1, %2" : "=v"(r) : "v"(a), "v"(b));
    return r;
}
__device__ __forceinline__ bf16x8 cvt8(float4 a, float4 b) {
    union { unsigned u[4]; bf16x8 v; } r;
    r.u[0] = pk2(a.x, a.y); r.u[1] = pk2(a.z, a.w);
    r.u[2] = pk2(b.x, b.y); r.u[3] = pk2(b.z, b.w);
    return r.v;
}

// ---------------------------------------------------------------------------
// Kernel A (MFMA): hb = bf16(x @ W^T + b), hb[0][:] = bf16(NEGV)
// Round-3 math; grid reshaped to 1 tile (16 rows) per wave -> 1563 blocks,
// ~6 blocks/CU (vs 3) to hide the scattered 16B A-fragment loads.
// C/D mapping col=lane&15, row=(lane>>4)*4+reg (m89/m91-verified).
// ---------------------------------------------------------------------------
__global__ __launch_bounds__(256) void h_kernel(const float* __restrict__ x,
                                                const float* __restrict__ W,
                                                const float* __restrict__ b,
                                                ushort* __restrict__ hb) {
    const int t    = threadIdx.x;
    const int w    = t >> 6;
    const int lane = t & 63;
    const int lr   = lane & 15;     // frag row (A) / col (B, C)
    const int lg   = lane >> 4;     // k-group

    bf16x8 Bf[4][4];
    const float* wp = W + (size_t)lr * DIN + lg * 8;
#pragma unroll
    for (int ct = 0; ct < 4; ++ct)
#pragma unroll
        for (int ks = 0; ks < 4; ++ks) {
            const float* p = wp + ct * 16 * DIN + ks * 32;
            Bf[ct][ks] = cvt8(*(const float4*)p, *(const float4*)(p + 4));
        }

    float bias[4];
#pragma unroll
    for (int ct = 0; ct < 4; ++ct) bias[ct] = b[ct * 16 + lr];

    const int row0 = blockIdx.x * 64 + w * 16;   // 1563 blocks * 64 rows

    int ar = row0 + lr;                          // A row for this lane
    if (ar > NN - 1) ar = NN - 1;                // clamp (result discarded)
    const float* xp = x + (size_t)ar * DIN + lg * 8;

    bf16x8 Af[4];
#pragma unroll
    for (int ks = 0; ks < 4; ++ks)
        Af[ks] = cvt8(*(const float4*)(xp + ks * 32),
                      *(const float4*)(xp + ks * 32 + 4));

    f32x4 acc[4] = {{0.f,0.f,0.f,0.f},{0.f,0.f,0.f,0.f},
                    {0.f,0.f,0.f,0.f},{0.f,0.f,0.f,0.f}};
#pragma unroll
    for (int ct = 0; ct < 4; ++ct)
#pragma unroll
        for (int ks = 0; ks < 4; ++ks)
            acc[ct] = __builtin_amdgcn_mfma_f32_16x16x32_bf16(
                Af[ks], Bf[ct][ks], acc[ct], 0, 0, 0);

#pragma unroll
    for (int ct = 0; ct < 4; ++ct)
#pragma unroll
        for (int j = 0; j < 4; ++j) {
            const int m = row0 + lg * 4 + j;
            if (m < NN) {
                const float v = (m == 0) ? NEGV : (acc[ct][j] + bias[ct]);
                hb[(size_t)m * DOUT + ct * 16 + lr] = f2bf(v);
            }
        }
}

// ---------------------------------------------------------------------------
// Kernel B (round-3 verbatim — measured 51.5 us, at the L2-miss service
// floor for this random-gather pattern): one wave per row; lane pair
// (2k,2k+1) splits neighbor k's 64-dim dot into 32-dim halves (4 x uint4 =
// 64B per lane from the bf16 table). f32 accumulation throughout.
// ---------------------------------------------------------------------------
__global__ __launch_bounds__(256) void att_kernel(const ushort* __restrict__ hb,
                                                  const int* __restrict__ a2a,
                                                  float* __restrict__ out) {
    const int t    = threadIdx.x;
    const int wid  = t >> 6;
    const int lane = t & 63;
    const int n    = blockIdx.x * 4 + wid;          // 25000 blocks * 4

    const ushort* hbn = hb + (size_t)n * DOUT;
    const float hv = bflo((unsigned)hbn[lane]);     // coalesced 128B row read

    float sp = hv * hv;                              // self-dot, 64 lanes
#pragma unroll
    for (int q = 1; q <= 32; q <<= 1) sp += __shfl_xor(sp, q);

    const int k    = lane >> 1;
    const int half = lane & 1;
    const int idx  = a2a[n * KK + k];

    const uint4* nb = reinterpret_cast<const uint4*>(hb + (size_t)idx * DOUT) + half * 4;
    const uint4* un = reinterpret_cast<const uint4*>(hbn) + half * 4;

    float d = 0.f;
#pragma unroll
    for (int i = 0; i < 4; ++i) {
        const uint4 v = nb[i];
        const uint4 u = un[i];
        d = fmaf(bflo(v.x), bflo(u.x), d); d = fmaf(bfhi(v.x), bfhi(u.x), d);
        d = fmaf(bflo(v.y), bflo(u.y), d); d = fmaf(bfhi(v.y), bfhi(u.y), d);
        d = fmaf(bflo(v.z), bflo(u.z), d); d = fmaf(bfhi(v.z), bfhi(u.z), d);
        d = fmaf(bflo(v.w), bflo(u.w), d); d = fmaf(bfhi(v.w), bfhi(u.w), d);
    }
    d += __shfl_xor(d, 1);     // pair now holds full dot_k

    float m = d;
#pragma unroll
    for (int q = 2; q <= 32; q <<= 1) m = fmaxf(m, __shfl_xor(m, q));
    m = fmaxf(m, sp);

    float e = __expf(d - m);
    float s = e;
#pragma unroll
    for (int q = 1; q <= 32; q <<= 1) s += __shfl_xor(s, q);
    s *= 0.5f;                 // each neighbor counted by both lanes of pair

    const float es = __expf(sp - m);
    const float w0 = es / (es + s);

    float o = hv * w0;
    if (n == 0) o = 0.f;
    out[(size_t)n * DOUT + lane] = o;
}

extern "C" void kernel_launch(void* const* d_in, const int* in_sizes, int n_in,
                              void* d_out, int out_size, void* d_ws, size_t ws_size,
                              hipStream_t stream) {
    const float* x   = (const float*)d_in[0];
    const int*   a2a = (const int*)d_in[1];
    const float* W   = (const float*)d_in[2];
    const float* b   = (const float*)d_in[3];
    float*       out = (float*)d_out;
    ushort*      hb  = (ushort*)d_ws;   // N*DOUT*2 = 12.8 MB bf16 table

    h_kernel<<<(NN + 63) / 64, 256, 0, stream>>>(x, W, b, hb);
    att_kernel<<<NN / 4, 256, 0, stream>>>(hb, a2a, out);
}